// Round 6
// baseline (235.000 us; speedup 1.0000x reference)
//
#include <hip/hip_runtime.h>
#include <math.h>

#define D 4096
#define NT 64                // one wave per block, one row per wave
#define EPS 1e-5f
#define EPS_SQRT 3.16227766016837933e-3f
#define LN2 0.69314718055994531f

// One wave per row, barrier-free. Row cache split: 32 floats/lane in VGPRs
// (budget ~70 regs -- R1 proved the allocator grants 72 spill-free with plain
// launch_bounds) + 8 KB in LDS -> 20 blocks/CU residency (vs 10 at 16 KB LDS).
__global__ __launch_bounds__(NT) void lnn_kernel(const float* __restrict__ x,
                                                 const float* __restrict__ w,
                                                 const float* __restrict__ b,
                                                 float* __restrict__ out,
                                                 int rows) {
    const int lane = threadIdx.x;        // 0..63
    const int row  = blockIdx.x;
    if (row >= rows) return;

    __shared__ float buf[D / 2];         // half the row: raw x, then copysign(L2,xs)
    float4* s4 = (float4*)buf;

    const float4* x4 = (const float4*)(x + (size_t)row * D);
    const float inv_d = 1.f / (float)D;

    // ---- pass 1: reg half (c=0..7) + LDS half (c=8..15); mean/var in flight ----
    float v[32];
    float s = 0.f, s2 = 0.f;
#pragma unroll
    for (int c = 0; c < 8; ++c) {
        float4 f = x4[c * 64 + lane];
        v[c*4+0] = f.x; v[c*4+1] = f.y; v[c*4+2] = f.z; v[c*4+3] = f.w;
        s += f.x; s2 = fmaf(f.x, f.x, s2);
        s += f.y; s2 = fmaf(f.y, f.y, s2);
        s += f.z; s2 = fmaf(f.z, f.z, s2);
        s += f.w; s2 = fmaf(f.w, f.w, s2);
    }
#pragma unroll
    for (int c = 0; c < 8; ++c) {
        float4 f = x4[(c + 8) * 64 + lane];
        s4[c * 64 + lane] = f;
        s += f.x; s2 = fmaf(f.x, f.x, s2);
        s += f.y; s2 = fmaf(f.y, f.y, s2);
        s += f.z; s2 = fmaf(f.z, f.z, s2);
        s += f.w; s2 = fmaf(f.w, f.w, s2);
    }
#pragma unroll
    for (int m = 32; m > 0; m >>= 1) {
        s  += __shfl_xor(s,  m, 64);
        s2 += __shfl_xor(s2, m, 64);
    }
    const float mean = s * inv_d;
    const float var  = s2 * inv_d - mean * mean;
    const float rstd = rsqrtf(var + EPS);
    const float nm   = -mean * rstd;

    // ---- pass 2: 5 row-sums; overwrite caches with sv = copysign(L2, xs) ----
    float s1 = 0.f, sxd = 0.f, sd = 0.f, sd2 = 0.f, sxd2 = 0.f;
    // reg half
#pragma unroll
    for (int i = 0; i < 32; ++i) {
        float xs   = fmaf(v[i], rstd, nm);
        float ab   = fabsf(xs);
        float onea = 1.f + ab;
        float L2   = __builtin_amdgcn_logf(onea);   // v_log_f32: log2(1+|xs|)
        float sv   = copysignf(L2, xs);
        v[i] = sv;
        s1 += sv;
        float l  = L2 * LN2;                         // natural log1p
        float dd = fmaf(onea, l, -ab);               // d = (1+|xs|)l1p - |xs|
        sxd = fmaf(xs, dd, sxd);
        sd += dd;
        sd2 = fmaf(dd, dd, sd2);
        float p1 = fmaf(onea, l * l, -(dd + dd));    // (1+|xs|)l1p^2 - 2d
        sxd2 = fmaf(ab, p1, sxd2);                   // xs*d2 = |xs|*p1
    }
    // LDS half
#pragma unroll
    for (int c = 0; c < 8; ++c) {
        float4 f = s4[c * 64 + lane];
        float e0[4] = {f.x, f.y, f.z, f.w};
        float sv[4];
#pragma unroll
        for (int j = 0; j < 4; ++j) {
            float xs   = fmaf(e0[j], rstd, nm);
            float ab   = fabsf(xs);
            float onea = 1.f + ab;
            float L2   = __builtin_amdgcn_logf(onea);
            float svj  = copysignf(L2, xs);
            sv[j] = svj;
            s1 += svj;
            float l  = L2 * LN2;
            float dd = fmaf(onea, l, -ab);
            sxd = fmaf(xs, dd, sxd);
            sd += dd;
            sd2 = fmaf(dd, dd, sd2);
            float p1 = fmaf(onea, l * l, -(dd + dd));
            sxd2 = fmaf(ab, p1, sxd2);
        }
        float4 o = {sv[0], sv[1], sv[2], sv[3]};
        s4[c * 64 + lane] = o;                       // same lane, same slot: safe
    }
#pragma unroll
    for (int m = 32; m > 0; m >>= 1) {
        s1   += __shfl_xor(s1,   m, 64);
        sxd  += __shfl_xor(sxd,  m, 64);
        sd   += __shfl_xor(sd,   m, 64);
        sd2  += __shfl_xor(sd2,  m, 64);
        sxd2 += __shfl_xor(sxd2, m, 64);
    }

    // ---- row scalars (every lane, redundant, cheap) ----
    const float s1m   = s1 * (inv_d * LN2);
    const float dvar  = 2.f * sxd * inv_d;
    const float g1    = 0.5f * dvar - s1m;
    const float dmean = sd * inv_d;
    const float vard  = sd2 * inv_d - dmean * dmean;
    const float d2var = 2.f * (sxd2 * inv_d + vard);
    const float g2    = -0.5f * dvar * dvar + 0.5f * d2var;
    const float lm    = 1.f - g1 * __builtin_amdgcn_rcpf(g2 + EPS_SQRT);

    const float eta_p = lm;
    const float eta_n = 2.f - lm;
    const float ep = eta_p + ((eta_p >= 0.f) ? EPS_SQRT : -EPS_SQRT);
    const float en = eta_n + ((eta_n >= 0.f) ? EPS_SQRT : -EPS_SQRT);
    const bool  mp = fabsf(eta_p) <= EPS_SQRT;
    const bool  mn = fabsf(eta_n) <= EPS_SQRT;
    const float rp =  __builtin_amdgcn_rcpf(ep);
    const float rn = -__builtin_amdgcn_rcpf(en);
    const bool fast = !(mp || mn);

    float* orow = out + (size_t)row * D;
    const float4* w4 = (const float4*)w;
    const float4* b4 = (const float4*)b;

    // ---- pass 3: transform + affine, store ----
    // reg half (c=0..7)
#pragma unroll
    for (int c = 0; c < 8; ++c) {
        float4 wf = w4[c * 64 + lane];
        float4 bf = b4[c * 64 + lane];
        float wa[4] = {wf.x, wf.y, wf.z, wf.w};
        float ba[4] = {bf.x, bf.y, bf.z, bf.w};
        float oa[4];
#pragma unroll
        for (int j = 0; j < 4; ++j) {
            float sv = v[c*4 + j];
            bool pos = (sv >= 0.f);
            float L2 = fabsf(sv);
            float e  = pos ? ep : en;
            float re = pos ? rp : rn;
            float tr = fmaf(re, __builtin_amdgcn_exp2f(e * L2), -re); // re*(2^(eL2)-1)
            if (!fast) {
                bool m = pos ? mp : mn;
                if (m) tr = sv * LN2;                // sign * l1p
            }
            oa[j] = fmaf(tr, wa[j], ba[j]);
        }
        float4 o = {oa[0], oa[1], oa[2], oa[3]};
        ((float4*)orow)[c * 64 + lane] = o;
    }
    // LDS half (c=8..15)
#pragma unroll
    for (int c = 0; c < 8; ++c) {
        float4 f  = s4[c * 64 + lane];
        float4 wf = w4[(c + 8) * 64 + lane];
        float4 bf = b4[(c + 8) * 64 + lane];
        float sva[4] = {f.x, f.y, f.z, f.w};
        float wa[4] = {wf.x, wf.y, wf.z, wf.w};
        float ba[4] = {bf.x, bf.y, bf.z, bf.w};
        float oa[4];
#pragma unroll
        for (int j = 0; j < 4; ++j) {
            float sv = sva[j];
            bool pos = (sv >= 0.f);
            float L2 = fabsf(sv);
            float e  = pos ? ep : en;
            float re = pos ? rp : rn;
            float tr = fmaf(re, __builtin_amdgcn_exp2f(e * L2), -re);
            if (!fast) {
                bool m = pos ? mp : mn;
                if (m) tr = sv * LN2;
            }
            oa[j] = fmaf(tr, wa[j], ba[j]);
        }
        float4 o = {oa[0], oa[1], oa[2], oa[3]};
        ((float4*)orow)[(c + 8) * 64 + lane] = o;
    }
}

extern "C" void kernel_launch(void* const* d_in, const int* in_sizes, int n_in,
                              void* d_out, int out_size, void* d_ws, size_t ws_size,
                              hipStream_t stream) {
    const float* x = (const float*)d_in[0];
    const float* w = (const float*)d_in[1];
    const float* b = (const float*)d_in[2];
    float* out = (float*)d_out;
    const int rows = in_sizes[0] / D;   // 8192
    lnn_kernel<<<dim3(rows), dim3(NT), 0, stream>>>(x, w, b, out, rows);
}